// Round 1
// baseline (179.281 us; speedup 1.0000x reference)
//
#include <hip/hip_runtime.h>

// SpacialSeparation: sum over j>i of (||o_i - o_j||^2)^(1/4) * (labels[i]!=labels[j] ? -1 : 5)
// b = 8192, d = 64, fp32 inputs, fp32 scalar output.
//
// Round 0: direct diff-square VALU kernel.
//  - 64x64-row tile pairs; one lane owns one i-row (64 floats in VGPRs).
//  - j-tile staged in LDS; per wave all lanes read the SAME j-row -> broadcast.
//  - Deterministic two-pass reduction via d_ws partials.

#define TILE 64

__global__ __launch_bounds__(256, 4)
void ss_pair_kernel(const float* __restrict__ O, const int* __restrict__ L,
                    float* __restrict__ partials, int nt) {
    const int ti = blockIdx.y;
    const int tj = blockIdx.x;
    const int slot = ti * nt + tj;
    const int tid = threadIdx.x;

    if (tj < ti) {            // lower-triangle tile: nothing to do
        if (tid == 0) partials[slot] = 0.0f;   // ws is poisoned -> must write
        return;
    }

    __shared__ float bs[TILE * 64];   // j-tile rows, 16 KiB
    __shared__ int   bl[TILE];        // j-tile labels
    __shared__ float wsum[4];

    // ---- stage j-tile (coalesced float4) ----
    const float4* src = (const float4*)(O + (size_t)tj * TILE * 64);
    float4* dst = (float4*)bs;
    #pragma unroll
    for (int idx = tid; idx < TILE * 16; idx += 256) dst[idx] = src[idx];
    if (tid < TILE) bl[tid] = L[tj * TILE + tid];

    const int wave = tid >> 6;
    const int lane = tid & 63;
    const int i = ti * TILE + lane;

    // ---- i-row into registers (64 floats / lane) ----
    float4 a[16];
    const float4* arow = (const float4*)(O + (size_t)i * 64);
    #pragma unroll
    for (int k = 0; k < 16; ++k) a[k] = arow[k];
    const int li = L[i];

    __syncthreads();

    float acc = 0.0f;
    // each wave handles 16 consecutive j-rows of the tile
    #pragma unroll 1
    for (int jj = 0; jj < 16; ++jj) {
        const int jl = wave * 16 + jj;
        const float4* brow = (const float4*)(bs + jl * 64);   // uniform addr -> broadcast
        float dx = 0.f, dy = 0.f, dz = 0.f, dw = 0.f;         // 4 independent chains
        #pragma unroll
        for (int k = 0; k < 16; ++k) {
            float4 bv = brow[k];
            float tx = a[k].x - bv.x; dx = fmaf(tx, tx, dx);
            float ty = a[k].y - bv.y; dy = fmaf(ty, ty, dy);
            float tz = a[k].z - bv.z; dz = fmaf(tz, tz, dz);
            float tw = a[k].w - bv.w; dw = fmaf(tw, tw, dw);
        }
        const float d2 = (dx + dy) + (dz + dw);
        const int j = tj * TILE + jl;
        const float dist = sqrtf(sqrtf(d2));                  // d2^(1/4)
        const float f = (li != bl[jl]) ? -1.0f : 5.0f;
        acc += (j > i) ? dist * f : 0.0f;                     // mask diagonal/lower
    }

    // ---- block reduction ----
    #pragma unroll
    for (int off = 32; off > 0; off >>= 1) acc += __shfl_down(acc, off);
    if (lane == 0) wsum[wave] = acc;
    __syncthreads();
    if (tid == 0) partials[slot] = (wsum[0] + wsum[1]) + (wsum[2] + wsum[3]);
}

__global__ void ss_reduce_kernel(const float* __restrict__ partials, int n,
                                 float* __restrict__ out) {
    __shared__ float s[4];
    const int tid = threadIdx.x;
    float acc = 0.0f;
    for (int idx = tid; idx < n; idx += 256) acc += partials[idx];
    #pragma unroll
    for (int off = 32; off > 0; off >>= 1) acc += __shfl_down(acc, off);
    if ((tid & 63) == 0) s[tid >> 6] = acc;
    __syncthreads();
    if (tid == 0) out[0] = (s[0] + s[1]) + (s[2] + s[3]);
}

extern "C" void kernel_launch(void* const* d_in, const int* in_sizes, int n_in,
                              void* d_out, int out_size, void* d_ws, size_t ws_size,
                              hipStream_t stream) {
    const float* O = (const float*)d_in[0];   // [b, 64] fp32
    const int*   L = (const int*)d_in[1];     // [b] int32
    float* out = (float*)d_out;               // scalar fp32

    const int b  = in_sizes[1];               // 8192
    const int nt = b / TILE;                  // 128

    float* partials = (float*)d_ws;           // nt*nt floats = 64 KiB

    dim3 grid(nt, nt);
    ss_pair_kernel<<<grid, 256, 0, stream>>>(O, L, partials, nt);
    ss_reduce_kernel<<<1, 256, 0, stream>>>(partials, nt * nt, out);
}

// Round 2
// 67.868 us; speedup vs baseline: 2.6416x; 2.6416x over previous
//
#include <hip/hip_runtime.h>

// SpacialSeparation: sum over j>i of (||o_i - o_j||^2)^(1/4) * (labels differ ? -1 : 5)
// b = 8192, d = 64, fp32 in, fp32 scalar out.
//
// Round 1: Gram-matrix reformulation on bf16 MFMA.
//   d2(i,j) = sq_i + sq_j - 2*dot(o_i, o_j), all from bf16-rounded values.
//   prep:   fp32 -> bf16 copy (RNE) + per-row squared norm (from rounded vals).
//   pair:   128x128 tile per block, 4 waves, each wave a 64x64 subtile via
//           16x16x32 bf16 MFMA (K=64 -> 2 mfma/frag, 32 mfma/wave).
//           Fragments loaded straight from global (1 MB bf16 -> L1/L2 resident).
//   epilogue in-register: d2 -> sqrt(sqrt()) -> +-1/5 factor -> masked sum.
//   two-pass deterministic reduction through d_ws.

typedef __bf16 bf16x8 __attribute__((ext_vector_type(8)));
typedef float  f32x4  __attribute__((ext_vector_type(4)));
typedef int    i32x4  __attribute__((ext_vector_type(4)));

#define BT 128   // block tile (128x128 pairs)

// ---- prep: convert to bf16 (RNE) and compute row squared norms ----
__global__ __launch_bounds__(256)
void ss_prep(const float* __restrict__ O, unsigned short* __restrict__ Obf,
             float* __restrict__ sqb) {
    const int row  = blockIdx.x * 4 + (threadIdx.x >> 6);
    const int lane = threadIdx.x & 63;
    const float v = O[(size_t)row * 64 + lane];
    const unsigned u = __builtin_bit_cast(unsigned, v);
    const unsigned rb = (u + 0x7fffu + ((u >> 16) & 1u)) >> 16;   // RNE to bf16
    Obf[(size_t)row * 64 + lane] = (unsigned short)rb;
    const float vb = __builtin_bit_cast(float, rb << 16);
    float s = vb * vb;
    #pragma unroll
    for (int off = 32; off > 0; off >>= 1) s += __shfl_down(s, off);
    if (lane == 0) sqb[row] = s;
}

// ---- main: fused Gram + epilogue ----
__global__ __launch_bounds__(256, 2)
void ss_mfma(const unsigned short* __restrict__ Obf, const float* __restrict__ sqb,
             const int* __restrict__ L, float* __restrict__ partials, int nt) {
    const int ti = blockIdx.y;
    const int tj = blockIdx.x;
    const int slot = ti * nt + tj;
    const int tid = threadIdx.x;

    if (tj < ti) {                       // lower-triangle tile: write 0, exit
        if (tid == 0) partials[slot] = 0.0f;
        return;
    }

    const int wave = tid >> 6;
    const int lane = tid & 63;
    const int wr = wave >> 1, wc = wave & 1;
    const int r0 = ti * BT + wr * 64;    // wave's i-row base
    const int c0 = tj * BT + wc * 64;    // wave's j-row base
    const int lrow = lane & 15;          // row/col within a 16x16 frag
    const int kb   = (lane >> 4) * 8;    // k-base within a K=32 chunk

    // ---- fragments straight from global (16B contiguous per lane) ----
    bf16x8 af[4][2], bfr[4][2];
    #pragma unroll
    for (int f = 0; f < 4; ++f) {
        const unsigned short* pa = Obf + (size_t)(r0 + f * 16 + lrow) * 64 + kb;
        const unsigned short* pb = Obf + (size_t)(c0 + f * 16 + lrow) * 64 + kb;
        af[f][0]  = *(const bf16x8*)(pa);
        af[f][1]  = *(const bf16x8*)(pa + 32);
        bfr[f][0] = *(const bf16x8*)(pb);
        bfr[f][1] = *(const bf16x8*)(pb + 32);
    }

    // ---- 64x64 Gram subtile: 16 frags x (K=64 -> 2 mfma) ----
    f32x4 acc[4][4];
    #pragma unroll
    for (int i = 0; i < 4; ++i)
        #pragma unroll
        for (int j = 0; j < 4; ++j)
            acc[i][j] = (f32x4){0.f, 0.f, 0.f, 0.f};

    #pragma unroll
    for (int i = 0; i < 4; ++i)
        #pragma unroll
        for (int j = 0; j < 4; ++j) {
            acc[i][j] = __builtin_amdgcn_mfma_f32_16x16x32_bf16(af[i][0], bfr[j][0], acc[i][j], 0, 0, 0);
            acc[i][j] = __builtin_amdgcn_mfma_f32_16x16x32_bf16(af[i][1], bfr[j][1], acc[i][j], 0, 0, 0);
        }

    // ---- per-lane metadata ----
    // C/D frag mapping: col = lane&15, row = (lane>>4)*4 + r   [m89]
    f32x4 sqi[4];  i32x4 li[4];
    #pragma unroll
    for (int f = 0; f < 4; ++f) {
        const int ib = r0 + f * 16 + ((lane >> 4) << 2);
        sqi[f] = *(const f32x4*)(sqb + ib);
        li[f]  = *(const i32x4*)(L + ib);
    }
    float sqj[4]; int lj[4];
    #pragma unroll
    for (int f = 0; f < 4; ++f) {
        const int j = c0 + f * 16 + lrow;
        sqj[f] = sqb[j];
        lj[f]  = L[j];
    }

    // ---- epilogue ----
    const bool diag = (ti == tj);
    float accs = 0.0f;
    #pragma unroll
    for (int fi = 0; fi < 4; ++fi) {
        const int ib = r0 + fi * 16 + ((lane >> 4) << 2);
        #pragma unroll
        for (int fj = 0; fj < 4; ++fj) {
            const int j = c0 + fj * 16 + lrow;
            const float sj = sqj[fj];
            const int   ljv = lj[fj];
            #pragma unroll
            for (int r = 0; r < 4; ++r) {
                const float g  = acc[fi][fj][r];
                float d2 = fmaf(-2.0f, g, sqi[fi][r] + sj);
                d2 = fmaxf(d2, 0.0f);
                const float dist = sqrtf(sqrtf(d2));       // d2^(1/4)
                const float fac  = (li[fi][r] != ljv) ? -1.0f : 5.0f;
                const bool keep  = (!diag) || (j > ib + r);
                accs += keep ? dist * fac : 0.0f;
            }
        }
    }

    // ---- block reduction ----
    __shared__ float wsum[4];
    #pragma unroll
    for (int off = 32; off > 0; off >>= 1) accs += __shfl_down(accs, off);
    if (lane == 0) wsum[wave] = accs;
    __syncthreads();
    if (tid == 0) partials[slot] = (wsum[0] + wsum[1]) + (wsum[2] + wsum[3]);
}

__global__ void ss_reduce_kernel(const float* __restrict__ partials, int n,
                                 float* __restrict__ out) {
    __shared__ float s[4];
    const int tid = threadIdx.x;
    float acc = 0.0f;
    for (int idx = tid; idx < n; idx += 256) acc += partials[idx];
    #pragma unroll
    for (int off = 32; off > 0; off >>= 1) acc += __shfl_down(acc, off);
    if ((tid & 63) == 0) s[tid >> 6] = acc;
    __syncthreads();
    if (tid == 0) out[0] = (s[0] + s[1]) + (s[2] + s[3]);
}

extern "C" void kernel_launch(void* const* d_in, const int* in_sizes, int n_in,
                              void* d_out, int out_size, void* d_ws, size_t ws_size,
                              hipStream_t stream) {
    const float* O = (const float*)d_in[0];   // [b, 64] fp32
    const int*   L = (const int*)d_in[1];     // [b] int32
    float* out = (float*)d_out;               // scalar fp32

    const int b  = in_sizes[1];               // 8192
    const int nt = b / BT;                    // 64

    // workspace layout
    char* ws = (char*)d_ws;
    float*          partials = (float*)ws;                      // nt*nt floats (16 KB)
    float*          sqb      = (float*)(ws + (64 << 10));       // b floats (32 KB)
    unsigned short* Obf      = (unsigned short*)(ws + (128 << 10)); // b*64 bf16 (1 MB)

    ss_prep<<<b / 4, 256, 0, stream>>>(O, Obf, sqb);
    dim3 grid(nt, nt);
    ss_mfma<<<grid, 256, 0, stream>>>(Obf, sqb, L, partials, nt);
    ss_reduce_kernel<<<1, 256, 0, stream>>>(partials, nt * nt, out);
}

// Round 4
// 44.819 us; speedup vs baseline: 4.0001x; 1.5143x over previous
//
#include <hip/hip_runtime.h>

// SpacialSeparation: sum over j>i of (||o_i - o_j||^2)^(1/4) * (labels differ ? -1 : 5)
// b = 8192, d = 64, fp32 in, fp32 scalar out.
//
// Round 3: round-2 kernel with the HIP-correct fast sqrt
// (__builtin_amdgcn_sqrtf -> raw v_sqrt_f32; __sqrtf doesn't exist in HIP).

typedef __bf16 bf16x8 __attribute__((ext_vector_type(8)));
typedef float  f32x4  __attribute__((ext_vector_type(4)));
typedef int    i32x4  __attribute__((ext_vector_type(4)));

#define BT 128

__device__ __forceinline__ float qroot(float x) {        // x^(1/4)
    return __builtin_amdgcn_sqrtf(__builtin_amdgcn_sqrtf(x));
}

// ---- prep: fp32 -> bf16 (RNE) + row squared norms of rounded values ----
__global__ __launch_bounds__(256)
void ss_prep(const float* __restrict__ O, unsigned short* __restrict__ Obf,
             float* __restrict__ sqb) {
    const int row  = blockIdx.x * 4 + (threadIdx.x >> 6);
    const int lane = threadIdx.x & 63;
    const float v = O[(size_t)row * 64 + lane];
    const unsigned u = __builtin_bit_cast(unsigned, v);
    const unsigned rb = (u + 0x7fffu + ((u >> 16) & 1u)) >> 16;   // RNE to bf16
    Obf[(size_t)row * 64 + lane] = (unsigned short)rb;
    const float vb = __builtin_bit_cast(float, rb << 16);
    float s = vb * vb;
    #pragma unroll
    for (int off = 32; off > 0; off >>= 1) s += __shfl_down(s, off);
    if (lane == 0) sqb[row] = s;
}

// ---- main: fused Gram + epilogue, triangular grid ----
__global__ __launch_bounds__(256, 4)
void ss_mfma(const unsigned short* __restrict__ Obf, const float* __restrict__ sqb,
             const int* __restrict__ L, float* __restrict__ partials, int nt) {
    // decode linear block id -> upper-tri tile (ti, tj), ti <= tj
    const int t = blockIdx.x;
    const float fnt = (float)nt + 0.5f;
    int ti = (int)floorf(fnt - sqrtf(fnt * fnt - 2.0f * (float)t));
    if (ti < 0) ti = 0;
    if (ti > nt - 1) ti = nt - 1;
    while (ti > 0 && ti * nt - (ti * (ti - 1)) / 2 > t) --ti;
    while ((ti + 1) * nt - ((ti + 1) * ti) / 2 <= t) ++ti;
    const int tj = ti + (t - (ti * nt - (ti * (ti - 1)) / 2));

    const int tid  = threadIdx.x;
    const int wave = tid >> 6, lane = tid & 63;
    const int wr = wave >> 1, wc = wave & 1;
    const bool diag = (ti == tj);

    const int r0 = ti * BT + wr * 64;    // wave's i-row base
    const int c0 = tj * BT + wc * 64;    // wave's j-row base
    const int lrow = lane & 15;
    const int kq = lane >> 4;            // 0..3
    const int kb = kq * 8;               // k element base within K=32 chunk

    float accs = 0.0f;

    if (!(diag && (wc < wr))) {          // skip fully-lower subtile of diag blocks
        // i-side metadata (C/D rows: (lane>>4)*4 + r  [m89])
        f32x4 sqi[4]; i32x4 li[4];
        #pragma unroll
        for (int f = 0; f < 4; ++f) {
            const int ib = r0 + f * 16 + (kq << 2);
            sqi[f] = *(const f32x4*)(sqb + ib);
            li[f]  = *(const i32x4*)(L + ib);
        }
        const bool masked = diag && (wr == wc);   // true diagonal 64x64 subtile

        #pragma unroll
        for (int jh = 0; jh < 2; ++jh) {          // two 64x32 j-halves
            const int cj = c0 + jh * 32;

            bf16x8 bfr[2][2];
            #pragma unroll
            for (int g = 0; g < 2; ++g) {
                const unsigned short* pb = Obf + (size_t)(cj + g * 16 + lrow) * 64 + kb;
                bfr[g][0] = *(const bf16x8*)pb;
                bfr[g][1] = *(const bf16x8*)(pb + 32);
            }

            f32x4 acc[4][2];
            #pragma unroll
            for (int i = 0; i < 4; ++i)
                #pragma unroll
                for (int g = 0; g < 2; ++g)
                    acc[i][g] = (f32x4){0.f, 0.f, 0.f, 0.f};

            #pragma unroll
            for (int i = 0; i < 4; ++i) {
                const unsigned short* pa = Obf + (size_t)(r0 + i * 16 + lrow) * 64 + kb;
                const bf16x8 a0 = *(const bf16x8*)pa;
                const bf16x8 a1 = *(const bf16x8*)(pa + 32);
                #pragma unroll
                for (int g = 0; g < 2; ++g) {
                    acc[i][g] = __builtin_amdgcn_mfma_f32_16x16x32_bf16(a0, bfr[g][0], acc[i][g], 0, 0, 0);
                    acc[i][g] = __builtin_amdgcn_mfma_f32_16x16x32_bf16(a1, bfr[g][1], acc[i][g], 0, 0, 0);
                }
            }

            // ---- epilogue ----
            #pragma unroll
            for (int g = 0; g < 2; ++g) {
                const int j   = cj + g * 16 + lrow;
                const float sj = sqb[j];
                const int  ljv = L[j];
                if (masked) {
                    #pragma unroll
                    for (int fi = 0; fi < 4; ++fi) {
                        const int ib = r0 + fi * 16 + (kq << 2);
                        #pragma unroll
                        for (int r = 0; r < 4; ++r) {
                            float d2 = fmaf(-2.0f, acc[fi][g][r], sqi[fi][r] + sj);
                            d2 = fmaxf(d2, 0.0f);
                            const float dist = qroot(d2);
                            const float fac  = (li[fi][r] != ljv) ? -1.0f : 5.0f;
                            accs += (j > ib + r) ? dist * fac : 0.0f;
                        }
                    }
                } else {
                    #pragma unroll
                    for (int fi = 0; fi < 4; ++fi) {
                        #pragma unroll
                        for (int r = 0; r < 4; ++r) {
                            float d2 = fmaf(-2.0f, acc[fi][g][r], sqi[fi][r] + sj);
                            d2 = fmaxf(d2, 0.0f);
                            const float dist = qroot(d2);
                            const float fac  = (li[fi][r] != ljv) ? -1.0f : 5.0f;
                            accs = fmaf(dist, fac, accs);
                        }
                    }
                }
            }
        }
    }

    // ---- block reduction ----
    __shared__ float wsum[4];
    #pragma unroll
    for (int off = 32; off > 0; off >>= 1) accs += __shfl_down(accs, off);
    if (lane == 0) wsum[wave] = accs;
    __syncthreads();
    if (tid == 0) partials[t] = (wsum[0] + wsum[1]) + (wsum[2] + wsum[3]);
}

__global__ void ss_reduce_kernel(const float* __restrict__ partials, int n,
                                 float* __restrict__ out) {
    __shared__ float s[4];
    const int tid = threadIdx.x;
    float acc = 0.0f;
    for (int idx = tid; idx < n; idx += 256) acc += partials[idx];
    #pragma unroll
    for (int off = 32; off > 0; off >>= 1) acc += __shfl_down(acc, off);
    if ((tid & 63) == 0) s[tid >> 6] = acc;
    __syncthreads();
    if (tid == 0) out[0] = (s[0] + s[1]) + (s[2] + s[3]);
}

extern "C" void kernel_launch(void* const* d_in, const int* in_sizes, int n_in,
                              void* d_out, int out_size, void* d_ws, size_t ws_size,
                              hipStream_t stream) {
    const float* O = (const float*)d_in[0];   // [b, 64] fp32
    const int*   L = (const int*)d_in[1];     // [b] int32
    float* out = (float*)d_out;               // scalar fp32

    const int b    = in_sizes[1];             // 8192
    const int nt   = b / BT;                  // 64
    const int ntri = nt * (nt + 1) / 2;       // 2080

    // workspace layout
    char* ws = (char*)d_ws;
    float*          partials = (float*)ws;                          // ntri floats
    float*          sqb      = (float*)(ws + (64 << 10));           // b floats
    unsigned short* Obf      = (unsigned short*)(ws + (128 << 10)); // b*64 bf16

    ss_prep<<<b / 4, 256, 0, stream>>>(O, Obf, sqb);
    ss_mfma<<<ntri, 256, 0, stream>>>(Obf, sqb, L, partials, nt);
    ss_reduce_kernel<<<1, 256, 0, stream>>>(partials, ntri, out);
}